// Round 15
// baseline (257.633 us; speedup 1.0000x reference)
//
#include <hip/hip_runtime.h>
#include <hip/hip_fp16.h>

static constexpr int TPB       = 256;
static constexpr int MAXB      = 64;            // max super-bins (N <= 256K at 4096/bin)
static constexpr int BIN_SHIFT = 12;            // 4096-node staging/record super-bin
static constexpr int BINSZ     = 1 << BIN_SHIFT;
static constexpr int SUB_SHIFT = 11;            // 2048-node accum subtile (24KB int LDS)
static constexpr int SUBSZ     = 1 << SUB_SHIFT;
static constexpr int NSUB      = BINSZ / SUBSZ; // 2
static constexpr int CAPB      = 176;           // per-(bin,block) region capacity (λ=128 +4.3σ)
static constexpr int NBLKS     = 2048;          // scatter blocks
static constexpr int SSL       = 16;            // block-region slices per (bin,subtile)
static constexpr int BPS       = NBLKS / SSL;   // block-regions per slice (128)
static constexpr int MAXG      = 64;
static constexpr int SLOTS     = MAXG * 6;      // 384 stress accumulators
static constexpr int NWAVES    = TPB / 64;

static constexpr float VSCALE  = 4096.0f;       // virial fixed-point (2^12)
static constexpr float VINV    = 1.0f / 4096.0f;
static constexpr float FSCALE  = 1048576.0f;    // force tile fixed-point (2^20)
static constexpr float FINV    = 1.0f / 1048576.0f;
static constexpr float OSCALE  = 65536.0f;      // overflow fixed-point (2^16)
static constexpr float OINV    = 1.0f / 65536.0f;

// ------------------------------------------------ zero overflow array
__global__ __launch_bounds__(TPB) void zero_ovf_kernel(int4* __restrict__ p4, long n4) {
    long i = (long)blockIdx.x * TPB + threadIdx.x;
    const long gs = (long)gridDim.x * TPB;
    for (; i < n4; i += gs) p4[i] = make_int4(0, 0, 0, 0);
}

// --------------------- A: merged scatter + virial (no staging, no barriers)
__device__ inline uint2 pack_rec(int node, float fx, float fy, float fz) {
    unsigned lid = (unsigned)node & (BINSZ - 1);    // 12-bit local id
    unsigned w0 = (unsigned)__half_as_ushort(__float2half(fx)) |
                  ((unsigned)__half_as_ushort(__float2half(fy)) << 16);
    unsigned w1 = (unsigned)__half_as_ushort(__float2half(fz)) | (lid << 16);
    return make_uint2(w0, w1);
}

__device__ inline void ovf_add(int* __restrict__ ovf, int node,
                               float fx, float fy, float fz) {
    atomicAdd(&ovf[3 * node + 0], __float2int_rn(fx * OSCALE));
    atomicAdd(&ovf[3 * node + 1], __float2int_rn(fy * OSCALE));
    atomicAdd(&ovf[3 * node + 2], __float2int_rn(fz * OSCALE));
}

__global__ __launch_bounds__(TPB) void scatter_kernel(
    const float* __restrict__ rij, const float* __restrict__ fij,
    const int* __restrict__ idx0, const int* __restrict__ idx1,
    const int* __restrict__ batch,
    uint2* __restrict__ rec, unsigned* __restrict__ cnt_out,
    int* __restrict__ ovf, float* __restrict__ apart,
    int E, int nbins) {
    __shared__ unsigned loc[MAXB];                 // per-bin slot counter (monotonic)
    __shared__ int s_acc[NWAVES][SLOTS];           // per-wave virial (6KB)

    for (int t = threadIdx.x; t < nbins; t += TPB) loc[t] = 0u;
    for (int t = threadIdx.x; t < NWAVES * SLOTS; t += TPB)
        ((int*)s_acc)[t] = 0;
    __syncthreads();

    const int NG = E >> 2;
    const int GC = (NG + NBLKS - 1) / NBLKS;
    const int g0 = blockIdx.x * GC;
    int g1 = g0 + GC; if (g1 > NG) g1 = NG;

    const float4* fij4 = (const float4*)fij;
    const float4* rij4 = (const float4*)rij;
    const int4* i04 = (const int4*)idx0;
    const int4* i14 = (const int4*)idx1;

    const int wid = threadIdx.x >> 6;
    int* my_acc = s_acc[wid];

    for (int k = g0 + threadIdx.x; k < g1; k += TPB) {
        int4 i0 = i04[k], i1 = i14[k];
        int s[4] = {i0.x, i0.y, i0.z, i0.w};
        int r[4] = {i1.x, i1.y, i1.z, i1.w};
        // early gather: batch values in flight while we pack/emit
        int gg[4];
#pragma unroll
        for (int e = 0; e < 4; ++e) gg[e] = batch[r[e]];

        float4 fa = fij4[3 * k], fb = fij4[3 * k + 1], fc = fij4[3 * k + 2];
        float4 ra = rij4[3 * k], rb = rij4[3 * k + 1], rc = rij4[3 * k + 2];
        float fx[4] = {fa.x, fa.w, fb.z, fc.y};
        float fy[4] = {fa.y, fb.x, fb.w, fc.z};
        float fz[4] = {fa.z, fb.y, fc.x, fc.w};
        float rx[4] = {ra.x, ra.w, rb.z, rc.y};
        float ry[4] = {ra.y, rb.x, rb.w, rc.z};
        float rz[4] = {ra.z, rb.y, rc.x, rc.w};

        // two-phase emit: pack all 8, issue all 8 LDS atomics, then all stores
        int bb[8]; uint2 wv[8]; unsigned slot[8];
#pragma unroll
        for (int e = 0; e < 4; ++e) {
            bb[2 * e] = s[e] >> BIN_SHIFT;
            wv[2 * e] = pack_rec(s[e], fx[e], fy[e], fz[e]);
            bb[2 * e + 1] = r[e] >> BIN_SHIFT;
            wv[2 * e + 1] = pack_rec(r[e], -fx[e], -fy[e], -fz[e]);
        }
#pragma unroll
        for (int j = 0; j < 8; ++j)
            slot[j] = atomicAdd(&loc[bb[j]], 1u);
#pragma unroll
        for (int j = 0; j < 8; ++j) {
            if (slot[j] < (unsigned)CAPB) {
                rec[((size_t)bb[j] * NBLKS + blockIdx.x) * CAPB + slot[j]] = wv[j];
            } else {
                // statistically-rare: spill to per-node overflow
                int node = (bb[j] << BIN_SHIFT) | (int)(wv[j].y >> 16);
                float ox = __half2float(__ushort_as_half((unsigned short)(wv[j].x & 0xffffu)));
                float oy = __half2float(__ushort_as_half((unsigned short)(wv[j].x >> 16)));
                float oz = __half2float(__ushort_as_half((unsigned short)(wv[j].y & 0xffffu)));
                ovf_add(ovf, node, ox, oy, oz);
            }
        }
        // virial (per-wave int fixed-point LDS atomics)
#pragma unroll
        for (int e = 0; e < 4; ++e) {
            int* a = &my_acc[6 * gg[e]];
            atomicAdd(&a[0], __float2int_rn(rx[e] * fx[e] * VSCALE));
            atomicAdd(&a[1], __float2int_rn(ry[e] * fy[e] * VSCALE));
            atomicAdd(&a[2], __float2int_rn(rz[e] * fz[e] * VSCALE));
            atomicAdd(&a[3], __float2int_rn(rx[e] * fy[e] * VSCALE));
            atomicAdd(&a[4], __float2int_rn(ry[e] * fz[e] * VSCALE));
            atomicAdd(&a[5], __float2int_rn(rz[e] * fx[e] * VSCALE));
        }
    }

    // scalar tail (E % 4): block 0, direct overflow path + virial
    if (blockIdx.x == 0) {
        for (int e = (NG << 2) + threadIdx.x; e < E; e += TPB) {
            float gx = fij[3 * e], gy = fij[3 * e + 1], gz = fij[3 * e + 2];
            int si = idx0[e], ri = idx1[e];
            ovf_add(ovf, si, gx, gy, gz);
            ovf_add(ovf, ri, -gx, -gy, -gz);
            float ex = rij[3 * e], ey = rij[3 * e + 1], ez = rij[3 * e + 2];
            int g = batch[ri];
            int* a = &my_acc[6 * g];
            atomicAdd(&a[0], __float2int_rn(ex * gx * VSCALE));
            atomicAdd(&a[1], __float2int_rn(ey * gy * VSCALE));
            atomicAdd(&a[2], __float2int_rn(ez * gz * VSCALE));
            atomicAdd(&a[3], __float2int_rn(ex * gy * VSCALE));
            atomicAdd(&a[4], __float2int_rn(ey * gz * VSCALE));
            atomicAdd(&a[5], __float2int_rn(ez * gx * VSCALE));
        }
    }

    __syncthreads();
    // per-(bin,block) record counts (clamped) + virial partials (wave-reduced)
    for (int t = threadIdx.x; t < nbins; t += TPB) {
        unsigned c = loc[t];
        cnt_out[(size_t)t * NBLKS + blockIdx.x] = c < (unsigned)CAPB ? c : (unsigned)CAPB;
    }
    for (int t = threadIdx.x; t < SLOTS; t += TPB) {
        int v = s_acc[0][t] + s_acc[1][t] + s_acc[2][t] + s_acc[3][t];
        apart[(size_t)t * NBLKS + blockIdx.x] = (float)v * VINV;
    }
}

// ------------------------------------------------------------- B: accumulate
__global__ __launch_bounds__(TPB) void bin_accum_kernel(
    const uint2* __restrict__ rec, const unsigned* __restrict__ cnt_out,
    float* __restrict__ bpart) {
    __shared__ int lf[SUBSZ * 3];                      // 24KB, fixed-point 2^20
    __shared__ unsigned scnt[BPS];
    const int sl = blockIdx.x % SSL;
    const int r2 = blockIdx.x / SSL;
    const int st = r2 & (NSUB - 1);
    const int bin = r2 >> 1;                           // NSUB == 2
    const int b0 = sl * BPS;

    int4* lf4 = (int4*)lf;
    for (int t = threadIdx.x; t < SUBSZ * 3 / 4; t += TPB)
        lf4[t] = make_int4(0, 0, 0, 0);
    // preload all region counts (one coalesced pass)
    for (int t = threadIdx.x; t < BPS; t += TPB)
        scnt[t] = cnt_out[(size_t)bin * NBLKS + b0 + t];
    __syncthreads();

    const int wid = threadIdx.x >> 6, lane = threadIdx.x & 63;

    // wave-per-region: 4 independent streams, full lane utilization
    for (int blk = wid; blk < BPS; blk += NWAVES) {
        unsigned c = scnt[blk];
        size_t base = ((size_t)bin * NBLKS + (b0 + blk)) * CAPB;
        for (unsigned r = (unsigned)lane; r < c; r += 64) {
            uint2 w = rec[base + r];
            unsigned lid = w.y >> 16;
            if ((int)(lid >> SUB_SHIFT) == st) {
                unsigned l2 = lid & (SUBSZ - 1);
                float fx = __half2float(__ushort_as_half((unsigned short)(w.x & 0xffffu)));
                float fy = __half2float(__ushort_as_half((unsigned short)(w.x >> 16)));
                float fz = __half2float(__ushort_as_half((unsigned short)(w.y & 0xffffu)));
                atomicAdd(&lf[l2 * 3 + 0], __float2int_rn(fx * FSCALE));
                atomicAdd(&lf[l2 * 3 + 1], __float2int_rn(fy * FSCALE));
                atomicAdd(&lf[l2 * 3 + 2], __float2int_rn(fz * FSCALE));
            }
        }
    }
    __syncthreads();
    float4* dst = (float4*)(bpart + (size_t)blockIdx.x * (SUBSZ * 3));
    for (int t = threadIdx.x; t < SUBSZ * 3 / 4; t += TPB) {
        int4 v = lf4[t];
        dst[t] = make_float4((float)v.x * FINV, (float)v.y * FINV,
                             (float)v.z * FINV, (float)v.w * FINV);
    }
}

// ------------------------------------------------------------- C: force out
__global__ __launch_bounds__(TPB) void force_kernel(
    const float* __restrict__ bpart, const int* __restrict__ ovf,
    const float* __restrict__ pos_grad,
    float* __restrict__ force, long n3) {
    long j = (long)blockIdx.x * TPB + threadIdx.x;
    const long gs = (long)gridDim.x * TPB;
    for (; j < n3; j += gs) {
        unsigned i = (unsigned)(j / 3);
        unsigned c = (unsigned)(j - 3L * i);
        unsigned bin = i >> BIN_SHIFT;
        unsigned st = (i >> SUB_SHIFT) & (NSUB - 1);
        unsigned l2 = i & (SUBSZ - 1);
        float acc = -pos_grad[j] + (float)ovf[j] * OINV;
        size_t tb = ((size_t)(bin * NSUB + st) * SSL) * (SUBSZ * 3) + l2 * 3 + c;
#pragma unroll
        for (int sl = 0; sl < SSL; ++sl)
            acc += bpart[tb + (size_t)sl * (SUBSZ * 3)];
        force[j] = acc;
    }
}

// ------------------------------------------------------------- R: stress out
__global__ __launch_bounds__(TPB) void stress_kernel(
    const float* __restrict__ apart,
    const float* __restrict__ cell_grad, const float* __restrict__ les_cell,
    const float* __restrict__ vol, float* __restrict__ stress, int slots) {
    int t = blockIdx.x;
    if (t >= slots) return;
    __shared__ float red[TPB];
    float s = 0.f;
    const float* row = apart + (size_t)t * NBLKS;
    for (int j = threadIdx.x; j < NBLKS; j += TPB) s += row[j];
    red[threadIdx.x] = s;
    __syncthreads();
    for (int w = TPB / 2; w > 0; w >>= 1) {
        if (threadIdx.x < w) red[threadIdx.x] += red[threadIdx.x + w];
        __syncthreads();
    }
    if (threadIdx.x == 0) {
        int g = t / 6, c = t - 6 * g;
        const int va[6] = {0, 1, 2, 0, 1, 0};
        const int vb[6] = {0, 1, 2, 1, 2, 2};
        int a = va[c], bb = vb[c];
        const float* L = les_cell + 9 * g;
        const float* Gm = cell_grad + 9 * g;
        float lr = L[a] * Gm[bb] + L[3 + a] * Gm[3 + bb] + L[6 + a] * Gm[6 + bb];
        stress[t] = (-red[0] - lr) / vol[g];
    }
}

// ---------------------------------------------------- fallback (round-1 path)
__global__ void init_force_kernel(const float4* __restrict__ pg4,
                                  float4* __restrict__ f4, int n4,
                                  const float* __restrict__ pg,
                                  float* __restrict__ f, int n) {
    int i = blockIdx.x * blockDim.x + threadIdx.x;
    int s = gridDim.x * blockDim.x;
    for (int k = i; k < n4; k += s) {
        float4 v = pg4[k];
        f4[k] = make_float4(-v.x, -v.y, -v.z, -v.w);
    }
    for (int k = n4 * 4 + i; k < n; k += s) f[k] = -pg[k];
}

__global__ __launch_bounds__(256) void edge_dev_kernel(
    const float* __restrict__ rij, const float* __restrict__ fij,
    const int* __restrict__ idx0, const int* __restrict__ idx1,
    const int* __restrict__ batch,
    float* __restrict__ force, float* __restrict__ partials, int E) {
    __shared__ float s_acc[SLOTS];
    for (int t = threadIdx.x; t < SLOTS; t += blockDim.x) s_acc[t] = 0.0f;
    __syncthreads();
    const int stride = gridDim.x * blockDim.x;
    const int tid0 = blockIdx.x * blockDim.x + threadIdx.x;
    for (int e = tid0; e < E; e += stride) {
        float ex = rij[3 * e], ey = rij[3 * e + 1], ez = rij[3 * e + 2];
        float gx = fij[3 * e], gy = fij[3 * e + 1], gz = fij[3 * e + 2];
        int si = idx0[e], ri = idx1[e];
        atomicAdd(&force[3 * si + 0], gx);
        atomicAdd(&force[3 * si + 1], gy);
        atomicAdd(&force[3 * si + 2], gz);
        atomicAdd(&force[3 * ri + 0], -gx);
        atomicAdd(&force[3 * ri + 1], -gy);
        atomicAdd(&force[3 * ri + 2], -gz);
        int g = batch[ri];
        float* a = &s_acc[6 * g];
        atomicAdd(&a[0], ex * gx);
        atomicAdd(&a[1], ey * gy);
        atomicAdd(&a[2], ez * gz);
        atomicAdd(&a[3], ex * gy);
        atomicAdd(&a[4], ey * gz);
        atomicAdd(&a[5], ez * gx);
    }
    __syncthreads();
    for (int t = threadIdx.x; t < SLOTS; t += blockDim.x)
        partials[(size_t)blockIdx.x * SLOTS + t] = s_acc[t];
}

__global__ void reduce_finalize_kernel(const float* __restrict__ partials, int nblocks,
                                       const float* __restrict__ cell_grad,
                                       const float* __restrict__ les_cell,
                                       const float* __restrict__ vol,
                                       float* __restrict__ stress_out, int slots) {
    int t = blockIdx.x * blockDim.x + threadIdx.x;
    if (t >= slots) return;
    float s = 0.0f;
    for (int b = 0; b < nblocks; ++b) s += partials[(size_t)b * SLOTS + t];
    int g = t / 6, c = t - 6 * g;
    const int va[6] = {0, 1, 2, 0, 1, 0};
    const int vb[6] = {0, 1, 2, 1, 2, 2};
    int a = va[c], bb = vb[c];
    const float* L = les_cell + 9 * g;
    const float* G = cell_grad + 9 * g;
    float lr = L[a] * G[bb] + L[3 + a] * G[3 + bb] + L[6 + a] * G[6 + bb];
    stress_out[t] = (-s - lr) / vol[g];
}

// ------------------------------------------------------------------ launcher
static inline size_t alignup(size_t x) { return (x + 255) & ~(size_t)255; }

extern "C" void kernel_launch(void* const* d_in, const int* in_sizes, int n_in,
                              void* d_out, int out_size, void* d_ws, size_t ws_size,
                              hipStream_t stream) {
    const float* rij = (const float*)d_in[0];
    const float* fij = (const float*)d_in[1];
    const float* pos_grad = (const float*)d_in[2];
    const float* cell_grad = (const float*)d_in[3];
    const float* les_cell = (const float*)d_in[4];
    const float* vol = (const float*)d_in[5];
    const int* edge_idx = (const int*)d_in[6];
    const int* batch = (const int*)d_in[7];

    const int E = in_sizes[0] / 3;
    const int N = in_sizes[2] / 3;
    const int ngr = in_sizes[5];
    const int slots = 6 * ngr;

    float* force = (float*)d_out;
    float* stress = (float*)d_out + (size_t)N * 3;

    const int nbins = (N + BINSZ - 1) >> BIN_SHIFT;
    const long N3 = (long)N * 3;

    const size_t rec_elems = (size_t)nbins * NBLKS * CAPB;

    // workspace layout
    size_t off = 0;
    const size_t o_rec = off;    off += alignup(rec_elems * 8);
    const size_t o_cnt = off;    off += alignup((size_t)nbins * NBLKS * 4);
    const size_t o_ovf = off;    off += alignup(((size_t)N3 + 4) * 4);
    const size_t o_apart = off;  off += alignup((size_t)SLOTS * NBLKS * 4);
    const size_t o_bpart = off;  off += alignup((size_t)nbins * NSUB * SSL * (SUBSZ * 3) * 4);
    const bool fit = (off <= ws_size) && (nbins <= MAXB) && (ngr <= MAXG) && (E >= 4);

    if (fit) {
        char* ws = (char*)d_ws;
        uint2* rec = (uint2*)(ws + o_rec);
        unsigned* cnt_out = (unsigned*)(ws + o_cnt);
        int* ovf = (int*)(ws + o_ovf);
        float* apart = (float*)(ws + o_apart);
        float* bpart = (float*)(ws + o_bpart);

        long n4 = (N3 + 3) / 4;
        int zb = (int)((n4 + TPB - 1) / TPB); if (zb > 2048) zb = 2048; if (zb < 1) zb = 1;
        zero_ovf_kernel<<<zb, TPB, 0, stream>>>((int4*)ovf, n4);

        scatter_kernel<<<NBLKS, TPB, 0, stream>>>(
            rij, fij, edge_idx, edge_idx + E, batch, rec, cnt_out, ovf, apart,
            E, nbins);

        bin_accum_kernel<<<nbins * NSUB * SSL, TPB, 0, stream>>>(rec, cnt_out, bpart);

        int fblocks = (int)((N3 + TPB - 1) / TPB);
        if (fblocks > 4096) fblocks = 4096;
        force_kernel<<<fblocks, TPB, 0, stream>>>(bpart, ovf, pos_grad, force, N3);

        stress_kernel<<<slots, TPB, 0, stream>>>(apart, cell_grad, les_cell, vol,
                                                 stress, slots);
    } else {
        // device-atomic fallback (proven correct, slow)
        float* partials = (float*)d_ws;
        int eblocks = 512;
        size_t need = (size_t)eblocks * SLOTS * sizeof(float);
        if (need > ws_size) {
            int fit2 = (int)(ws_size / (SLOTS * sizeof(float)));
            eblocks = fit2 > 0 ? fit2 : 1;
        }
        int n = (int)N3, n4 = n / 4;
        int blocks = (n4 + 255) / 256;
        if (blocks > 1024) blocks = 1024;
        if (blocks < 1) blocks = 1;
        init_force_kernel<<<blocks, 256, 0, stream>>>(
            (const float4*)pos_grad, (float4*)force, n4, pos_grad, force, n);
        edge_dev_kernel<<<eblocks, 256, 0, stream>>>(rij, fij, edge_idx, edge_idx + E,
                                                     batch, force, partials, E);
        reduce_finalize_kernel<<<6, 64, 0, stream>>>(partials, eblocks, cell_grad,
                                                     les_cell, vol, stress, slots);
    }
}

// Round 16
// 218.038 us; speedup vs baseline: 1.1816x; 1.1816x over previous
//
#include <hip/hip_runtime.h>
#include <hip/hip_fp16.h>

static constexpr int TPB       = 256;
static constexpr int MAXB      = 64;            // max super-bins (N <= 256K at 4096/bin)
static constexpr int BIN_SHIFT = 12;            // 4096-node staging/record super-bin
static constexpr int BINSZ     = 1 << BIN_SHIFT;
static constexpr int SUB_SHIFT = 11;            // 2048-node accum subtile (24KB int LDS)
static constexpr int SUBSZ     = 1 << SUB_SHIFT;
static constexpr int NSUB      = BINSZ / SUBSZ; // 2
static constexpr int CAP       = 56;            // LDS bucket depth per super-bin (λ+2.2σ)
static constexpr int BSTRIDE   = 57;            // padded bucket stride (456B: breaks bank alignment)
static constexpr int CAPB      = 176;           // per-(bin,block) region capacity (λ=128 +4.2σ)
static constexpr int NBLKS     = 2048;          // scatter blocks
static constexpr int SSL       = 16;            // block-region slices per (bin,subtile)
static constexpr int BPS       = NBLKS / SSL;   // block-regions per slice (128)
static constexpr int MAXG      = 64;
static constexpr int SLOTS     = MAXG * 6;      // 384 stress accumulators
static constexpr int NWAVES    = TPB / 64;

static constexpr float VSCALE  = 4096.0f;       // virial fixed-point (2^12)
static constexpr float VINV    = 1.0f / 4096.0f;
static constexpr float FSCALE  = 1048576.0f;    // force tile fixed-point (2^20)
static constexpr float FINV    = 1.0f / 1048576.0f;
static constexpr float OSCALE  = 65536.0f;      // overflow fixed-point (2^16)
static constexpr float OINV    = 1.0f / 65536.0f;

// ------------------------------------------------ zero overflow array
__global__ __launch_bounds__(TPB) void zero_ovf_kernel(int4* __restrict__ p4, long n4) {
    long i = (long)blockIdx.x * TPB + threadIdx.x;
    const long gs = (long)gridDim.x * TPB;
    for (; i < n4; i += gs) p4[i] = make_int4(0, 0, 0, 0);
}

// --------------------- A: merged scatter + virial (staged, padded buckets)
__device__ inline uint2 pack_rec(int node, float fx, float fy, float fz) {
    unsigned lid = (unsigned)node & (BINSZ - 1);    // 12-bit local id
    unsigned w0 = (unsigned)__half_as_ushort(__float2half(fx)) |
                  ((unsigned)__half_as_ushort(__float2half(fy)) << 16);
    unsigned w1 = (unsigned)__half_as_ushort(__float2half(fz)) | (lid << 16);
    return make_uint2(w0, w1);
}

__device__ inline void ovf_add(int* __restrict__ ovf, int node,
                               float fx, float fy, float fz) {
    atomicAdd(&ovf[3 * node + 0], __float2int_rn(fx * OSCALE));
    atomicAdd(&ovf[3 * node + 1], __float2int_rn(fy * OSCALE));
    atomicAdd(&ovf[3 * node + 2], __float2int_rn(fz * OSCALE));
}

__global__ __launch_bounds__(TPB) void scatter_kernel(
    const float* __restrict__ rij, const float* __restrict__ fij,
    const int* __restrict__ idx0, const int* __restrict__ idx1,
    const int* __restrict__ batch,
    uint2* __restrict__ rec, unsigned* __restrict__ cnt_out,
    int* __restrict__ ovf, float* __restrict__ apart,
    int E, int nbins) {
    extern __shared__ char smem[];
    uint2* buf = (uint2*)smem;                                   // nbins*BSTRIDE
    unsigned* cnt = (unsigned*)(buf + (size_t)nbins * BSTRIDE);  // nbins
    unsigned* loc = cnt + nbins;                                 // nbins
    int* s_acc = (int*)(loc + nbins);                            // SLOTS (int)

    for (int t = threadIdx.x; t < nbins; t += TPB) { cnt[t] = 0u; loc[t] = 0u; }
    for (int t = threadIdx.x; t < SLOTS; t += TPB) s_acc[t] = 0;
    __syncthreads();

    const int NG = E >> 2;
    const int GC = (NG + NBLKS - 1) / NBLKS;
    const int g0 = blockIdx.x * GC;
    int g1 = g0 + GC; if (g1 > NG) g1 = NG;
    const int span = g1 - g0;
    const int niter = span > 0 ? (span + TPB - 1) / TPB : 0;

    const float4* fij4 = (const float4*)fij;
    const float4* rij4 = (const float4*)rij;
    const int4* i04 = (const int4*)idx0;
    const int4* i14 = (const int4*)idx1;

    const int wid = threadIdx.x >> 6, lane = threadIdx.x & 63;

    for (int it = 0; it < niter; ++it) {
        int k = g0 + it * TPB + threadIdx.x;
        if (k < g1) {
            int4 i0 = i04[k], i1 = i14[k];
            int s[4] = {i0.x, i0.y, i0.z, i0.w};
            int r[4] = {i1.x, i1.y, i1.z, i1.w};
            // early gather: batch values in flight while we pack/emit
            int gg[4];
#pragma unroll
            for (int e = 0; e < 4; ++e) gg[e] = batch[r[e]];

            float4 fa = fij4[3 * k], fb = fij4[3 * k + 1], fc = fij4[3 * k + 2];
            float4 ra = rij4[3 * k], rb = rij4[3 * k + 1], rc = rij4[3 * k + 2];
            float fx[4] = {fa.x, fa.w, fb.z, fc.y};
            float fy[4] = {fa.y, fb.x, fb.w, fc.z};
            float fz[4] = {fa.z, fb.y, fc.x, fc.w};
            float rx[4] = {ra.x, ra.w, rb.z, rc.y};
            float ry[4] = {ra.y, rb.x, rb.w, rc.z};
            float rz[4] = {ra.z, rb.y, rc.x, rc.w};

            // two-phase emit: pack all 8, issue all 8 LDS atomics, then stores
            int bb[8]; uint2 wv[8]; unsigned slot[8];
#pragma unroll
            for (int e = 0; e < 4; ++e) {
                bb[2 * e] = s[e] >> BIN_SHIFT;
                wv[2 * e] = pack_rec(s[e], fx[e], fy[e], fz[e]);
                bb[2 * e + 1] = r[e] >> BIN_SHIFT;
                wv[2 * e + 1] = pack_rec(r[e], -fx[e], -fy[e], -fz[e]);
            }
#pragma unroll
            for (int j = 0; j < 8; ++j)
                slot[j] = atomicAdd(&cnt[bb[j]], 1u);
#pragma unroll
            for (int j = 0; j < 8; ++j) {
                if (slot[j] < (unsigned)CAP) {
                    buf[bb[j] * BSTRIDE + slot[j]] = wv[j];
                } else {
                    // rare spill: per-node overflow accumulator
                    int node = (bb[j] << BIN_SHIFT) | (int)(wv[j].y >> 16);
                    float ox = __half2float(__ushort_as_half((unsigned short)(wv[j].x & 0xffffu)));
                    float oy = __half2float(__ushort_as_half((unsigned short)(wv[j].x >> 16)));
                    float oz = __half2float(__ushort_as_half((unsigned short)(wv[j].y & 0xffffu)));
                    ovf_add(ovf, node, ox, oy, oz);
                }
            }
            // virial (int fixed-point LDS atomics)
#pragma unroll
            for (int e = 0; e < 4; ++e) {
                int* a = &s_acc[6 * gg[e]];
                atomicAdd(&a[0], __float2int_rn(rx[e] * fx[e] * VSCALE));
                atomicAdd(&a[1], __float2int_rn(ry[e] * fy[e] * VSCALE));
                atomicAdd(&a[2], __float2int_rn(rz[e] * fz[e] * VSCALE));
                atomicAdd(&a[3], __float2int_rn(rx[e] * fy[e] * VSCALE));
                atomicAdd(&a[4], __float2int_rn(ry[e] * fz[e] * VSCALE));
                atomicAdd(&a[5], __float2int_rn(rz[e] * fx[e] * VSCALE));
            }
        }
        __syncthreads();
        // flush: coalesced wave stores into this block's fixed per-bin region
        for (int b = wid; b < nbins; b += NWAVES) {
            unsigned c = cnt[b];
            unsigned m = c < (unsigned)CAP ? c : (unsigned)CAP;
            unsigned off0 = loc[b];
            if ((unsigned)lane < m) {
                unsigned sl_ = off0 + (unsigned)lane;
                uint2 w = buf[b * BSTRIDE + lane];
                if (sl_ < (unsigned)CAPB) {
                    rec[((size_t)b * NBLKS + blockIdx.x) * CAPB + sl_] = w;
                } else {
                    int node = (b << BIN_SHIFT) | (int)(w.y >> 16);
                    float ox = __half2float(__ushort_as_half((unsigned short)(w.x & 0xffffu)));
                    float oy = __half2float(__ushort_as_half((unsigned short)(w.x >> 16)));
                    float oz = __half2float(__ushort_as_half((unsigned short)(w.y & 0xffffu)));
                    ovf_add(ovf, node, ox, oy, oz);
                }
            }
            if (lane == 0) {
                unsigned no = off0 + m;
                loc[b] = no < (unsigned)CAPB ? no : (unsigned)CAPB;
                cnt[b] = 0u;
            }
        }
        __syncthreads();
    }

    // scalar tail (E % 4): block 0, direct overflow path + virial
    if (blockIdx.x == 0) {
        for (int e = (NG << 2) + threadIdx.x; e < E; e += TPB) {
            float gx = fij[3 * e], gy = fij[3 * e + 1], gz = fij[3 * e + 2];
            int si = idx0[e], ri = idx1[e];
            ovf_add(ovf, si, gx, gy, gz);
            ovf_add(ovf, ri, -gx, -gy, -gz);
            float ex = rij[3 * e], ey = rij[3 * e + 1], ez = rij[3 * e + 2];
            int g = batch[ri];
            int* a = &s_acc[6 * g];
            atomicAdd(&a[0], __float2int_rn(ex * gx * VSCALE));
            atomicAdd(&a[1], __float2int_rn(ey * gy * VSCALE));
            atomicAdd(&a[2], __float2int_rn(ez * gz * VSCALE));
            atomicAdd(&a[3], __float2int_rn(ex * gy * VSCALE));
            atomicAdd(&a[4], __float2int_rn(ey * gz * VSCALE));
            atomicAdd(&a[5], __float2int_rn(ez * gx * VSCALE));
        }
    }

    __syncthreads();
    // per-(bin,block) record counts + virial partials
    for (int t = threadIdx.x; t < nbins; t += TPB)
        cnt_out[(size_t)t * NBLKS + blockIdx.x] = loc[t];
    for (int t = threadIdx.x; t < SLOTS; t += TPB)
        apart[(size_t)t * NBLKS + blockIdx.x] = (float)s_acc[t] * VINV;
}

// ------------------------------------------------------------- B: accumulate
__global__ __launch_bounds__(TPB) void bin_accum_kernel(
    const uint2* __restrict__ rec, const unsigned* __restrict__ cnt_out,
    float* __restrict__ bpart) {
    __shared__ int lf[SUBSZ * 3];                      // 24KB, fixed-point 2^20
    __shared__ unsigned scnt[BPS];
    const int sl = blockIdx.x % SSL;
    const int r2 = blockIdx.x / SSL;
    const int st = r2 & (NSUB - 1);
    const int bin = r2 >> 1;                           // NSUB == 2
    const int b0 = sl * BPS;

    int4* lf4 = (int4*)lf;
    for (int t = threadIdx.x; t < SUBSZ * 3 / 4; t += TPB)
        lf4[t] = make_int4(0, 0, 0, 0);
    // preload all region counts (one coalesced pass)
    for (int t = threadIdx.x; t < BPS; t += TPB)
        scnt[t] = cnt_out[(size_t)bin * NBLKS + b0 + t];
    __syncthreads();

    const int wid = threadIdx.x >> 6, lane = threadIdx.x & 63;

    // wave-per-region: 4 independent streams, full lane utilization
    for (int blk = wid; blk < BPS; blk += NWAVES) {
        unsigned c = scnt[blk];
        size_t base = ((size_t)bin * NBLKS + (b0 + blk)) * CAPB;
        for (unsigned r = (unsigned)lane; r < c; r += 64) {
            uint2 w = rec[base + r];
            unsigned lid = w.y >> 16;
            if ((int)(lid >> SUB_SHIFT) == st) {
                unsigned l2 = lid & (SUBSZ - 1);
                float fx = __half2float(__ushort_as_half((unsigned short)(w.x & 0xffffu)));
                float fy = __half2float(__ushort_as_half((unsigned short)(w.x >> 16)));
                float fz = __half2float(__ushort_as_half((unsigned short)(w.y & 0xffffu)));
                atomicAdd(&lf[l2 * 3 + 0], __float2int_rn(fx * FSCALE));
                atomicAdd(&lf[l2 * 3 + 1], __float2int_rn(fy * FSCALE));
                atomicAdd(&lf[l2 * 3 + 2], __float2int_rn(fz * FSCALE));
            }
        }
    }
    __syncthreads();
    float4* dst = (float4*)(bpart + (size_t)blockIdx.x * (SUBSZ * 3));
    for (int t = threadIdx.x; t < SUBSZ * 3 / 4; t += TPB) {
        int4 v = lf4[t];
        dst[t] = make_float4((float)v.x * FINV, (float)v.y * FINV,
                             (float)v.z * FINV, (float)v.w * FINV);
    }
}

// ------------------------------------------------------------- C: force out
__global__ __launch_bounds__(TPB) void force_kernel(
    const float* __restrict__ bpart, const int* __restrict__ ovf,
    const float* __restrict__ pos_grad,
    float* __restrict__ force, long n3) {
    long j = (long)blockIdx.x * TPB + threadIdx.x;
    const long gs = (long)gridDim.x * TPB;
    for (; j < n3; j += gs) {
        unsigned i = (unsigned)(j / 3);
        unsigned c = (unsigned)(j - 3L * i);
        unsigned bin = i >> BIN_SHIFT;
        unsigned st = (i >> SUB_SHIFT) & (NSUB - 1);
        unsigned l2 = i & (SUBSZ - 1);
        float acc = -pos_grad[j] + (float)ovf[j] * OINV;
        size_t tb = ((size_t)(bin * NSUB + st) * SSL) * (SUBSZ * 3) + l2 * 3 + c;
#pragma unroll
        for (int sl = 0; sl < SSL; ++sl)
            acc += bpart[tb + (size_t)sl * (SUBSZ * 3)];
        force[j] = acc;
    }
}

// ------------------------------------------------------------- R: stress out
__global__ __launch_bounds__(TPB) void stress_kernel(
    const float* __restrict__ apart,
    const float* __restrict__ cell_grad, const float* __restrict__ les_cell,
    const float* __restrict__ vol, float* __restrict__ stress, int slots) {
    int t = blockIdx.x;
    if (t >= slots) return;
    __shared__ float red[TPB];
    float s = 0.f;
    const float* row = apart + (size_t)t * NBLKS;
    for (int j = threadIdx.x; j < NBLKS; j += TPB) s += row[j];
    red[threadIdx.x] = s;
    __syncthreads();
    for (int w = TPB / 2; w > 0; w >>= 1) {
        if (threadIdx.x < w) red[threadIdx.x] += red[threadIdx.x + w];
        __syncthreads();
    }
    if (threadIdx.x == 0) {
        int g = t / 6, c = t - 6 * g;
        const int va[6] = {0, 1, 2, 0, 1, 0};
        const int vb[6] = {0, 1, 2, 1, 2, 2};
        int a = va[c], bb = vb[c];
        const float* L = les_cell + 9 * g;
        const float* Gm = cell_grad + 9 * g;
        float lr = L[a] * Gm[bb] + L[3 + a] * Gm[3 + bb] + L[6 + a] * Gm[6 + bb];
        stress[t] = (-red[0] - lr) / vol[g];
    }
}

// ---------------------------------------------------- fallback (round-1 path)
__global__ void init_force_kernel(const float4* __restrict__ pg4,
                                  float4* __restrict__ f4, int n4,
                                  const float* __restrict__ pg,
                                  float* __restrict__ f, int n) {
    int i = blockIdx.x * blockDim.x + threadIdx.x;
    int s = gridDim.x * blockDim.x;
    for (int k = i; k < n4; k += s) {
        float4 v = pg4[k];
        f4[k] = make_float4(-v.x, -v.y, -v.z, -v.w);
    }
    for (int k = n4 * 4 + i; k < n; k += s) f[k] = -pg[k];
}

__global__ __launch_bounds__(256) void edge_dev_kernel(
    const float* __restrict__ rij, const float* __restrict__ fij,
    const int* __restrict__ idx0, const int* __restrict__ idx1,
    const int* __restrict__ batch,
    float* __restrict__ force, float* __restrict__ partials, int E) {
    __shared__ float s_acc[SLOTS];
    for (int t = threadIdx.x; t < SLOTS; t += blockDim.x) s_acc[t] = 0.0f;
    __syncthreads();
    const int stride = gridDim.x * blockDim.x;
    const int tid0 = blockIdx.x * blockDim.x + threadIdx.x;
    for (int e = tid0; e < E; e += stride) {
        float ex = rij[3 * e], ey = rij[3 * e + 1], ez = rij[3 * e + 2];
        float gx = fij[3 * e], gy = fij[3 * e + 1], gz = fij[3 * e + 2];
        int si = idx0[e], ri = idx1[e];
        atomicAdd(&force[3 * si + 0], gx);
        atomicAdd(&force[3 * si + 1], gy);
        atomicAdd(&force[3 * si + 2], gz);
        atomicAdd(&force[3 * ri + 0], -gx);
        atomicAdd(&force[3 * ri + 1], -gy);
        atomicAdd(&force[3 * ri + 2], -gz);
        int g = batch[ri];
        float* a = &s_acc[6 * g];
        atomicAdd(&a[0], ex * gx);
        atomicAdd(&a[1], ey * gy);
        atomicAdd(&a[2], ez * gz);
        atomicAdd(&a[3], ex * gy);
        atomicAdd(&a[4], ey * gz);
        atomicAdd(&a[5], ez * gx);
    }
    __syncthreads();
    for (int t = threadIdx.x; t < SLOTS; t += blockDim.x)
        partials[(size_t)blockIdx.x * SLOTS + t] = s_acc[t];
}

__global__ void reduce_finalize_kernel(const float* __restrict__ partials, int nblocks,
                                       const float* __restrict__ cell_grad,
                                       const float* __restrict__ les_cell,
                                       const float* __restrict__ vol,
                                       float* __restrict__ stress_out, int slots) {
    int t = blockIdx.x * blockDim.x + threadIdx.x;
    if (t >= slots) return;
    float s = 0.0f;
    for (int b = 0; b < nblocks; ++b) s += partials[(size_t)b * SLOTS + t];
    int g = t / 6, c = t - 6 * g;
    const int va[6] = {0, 1, 2, 0, 1, 0};
    const int vb[6] = {0, 1, 2, 1, 2, 2};
    int a = va[c], bb = vb[c];
    const float* L = les_cell + 9 * g;
    const float* G = cell_grad + 9 * g;
    float lr = L[a] * G[bb] + L[3 + a] * G[3 + bb] + L[6 + a] * G[6 + bb];
    stress_out[t] = (-s - lr) / vol[g];
}

// ------------------------------------------------------------------ launcher
static inline size_t alignup(size_t x) { return (x + 255) & ~(size_t)255; }

extern "C" void kernel_launch(void* const* d_in, const int* in_sizes, int n_in,
                              void* d_out, int out_size, void* d_ws, size_t ws_size,
                              hipStream_t stream) {
    const float* rij = (const float*)d_in[0];
    const float* fij = (const float*)d_in[1];
    const float* pos_grad = (const float*)d_in[2];
    const float* cell_grad = (const float*)d_in[3];
    const float* les_cell = (const float*)d_in[4];
    const float* vol = (const float*)d_in[5];
    const int* edge_idx = (const int*)d_in[6];
    const int* batch = (const int*)d_in[7];

    const int E = in_sizes[0] / 3;
    const int N = in_sizes[2] / 3;
    const int ngr = in_sizes[5];
    const int slots = 6 * ngr;

    float* force = (float*)d_out;
    float* stress = (float*)d_out + (size_t)N * 3;

    const int nbins = (N + BINSZ - 1) >> BIN_SHIFT;
    const long N3 = (long)N * 3;

    const size_t rec_elems = (size_t)nbins * NBLKS * CAPB;

    // workspace layout
    size_t off = 0;
    const size_t o_rec = off;    off += alignup(rec_elems * 8);
    const size_t o_cnt = off;    off += alignup((size_t)nbins * NBLKS * 4);
    const size_t o_ovf = off;    off += alignup(((size_t)N3 + 4) * 4);
    const size_t o_apart = off;  off += alignup((size_t)SLOTS * NBLKS * 4);
    const size_t o_bpart = off;  off += alignup((size_t)nbins * NSUB * SSL * (SUBSZ * 3) * 4);
    const bool fit = (off <= ws_size) && (nbins <= MAXB) && (ngr <= MAXG) && (E >= 4);

    if (fit) {
        char* ws = (char*)d_ws;
        uint2* rec = (uint2*)(ws + o_rec);
        unsigned* cnt_out = (unsigned*)(ws + o_cnt);
        int* ovf = (int*)(ws + o_ovf);
        float* apart = (float*)(ws + o_apart);
        float* bpart = (float*)(ws + o_bpart);

        long n4 = (N3 + 3) / 4;
        int zb = (int)((n4 + TPB - 1) / TPB); if (zb > 2048) zb = 2048; if (zb < 1) zb = 1;
        zero_ovf_kernel<<<zb, TPB, 0, stream>>>((int4*)ovf, n4);

        const size_t smem = (size_t)nbins * BSTRIDE * 8 + (size_t)nbins * 8 + SLOTS * 4;
        scatter_kernel<<<NBLKS, TPB, smem, stream>>>(
            rij, fij, edge_idx, edge_idx + E, batch, rec, cnt_out, ovf, apart,
            E, nbins);

        bin_accum_kernel<<<nbins * NSUB * SSL, TPB, 0, stream>>>(rec, cnt_out, bpart);

        int fblocks = (int)((N3 + TPB - 1) / TPB);
        if (fblocks > 4096) fblocks = 4096;
        force_kernel<<<fblocks, TPB, 0, stream>>>(bpart, ovf, pos_grad, force, N3);

        stress_kernel<<<slots, TPB, 0, stream>>>(apart, cell_grad, les_cell, vol,
                                                 stress, slots);
    } else {
        // device-atomic fallback (proven correct, slow)
        float* partials = (float*)d_ws;
        int eblocks = 512;
        size_t need = (size_t)eblocks * SLOTS * sizeof(float);
        if (need > ws_size) {
            int fit2 = (int)(ws_size / (SLOTS * sizeof(float)));
            eblocks = fit2 > 0 ? fit2 : 1;
        }
        int n = (int)N3, n4 = n / 4;
        int blocks = (n4 + 255) / 256;
        if (blocks > 1024) blocks = 1024;
        if (blocks < 1) blocks = 1;
        init_force_kernel<<<blocks, 256, 0, stream>>>(
            (const float4*)pos_grad, (float4*)force, n4, pos_grad, force, n);
        edge_dev_kernel<<<eblocks, 256, 0, stream>>>(rij, fij, edge_idx, edge_idx + E,
                                                     batch, force, partials, E);
        reduce_finalize_kernel<<<6, 64, 0, stream>>>(partials, eblocks, cell_grad,
                                                     les_cell, vol, stress, slots);
    }
}

// Round 17
// 215.517 us; speedup vs baseline: 1.1954x; 1.0117x over previous
//
#include <hip/hip_runtime.h>
#include <hip/hip_fp16.h>

static constexpr int TPB       = 256;
static constexpr int MAXB      = 64;            // max super-bins (N <= 256K at 4096/bin)
static constexpr int BIN_SHIFT = 12;            // 4096-node staging/record super-bin
static constexpr int BINSZ     = 1 << BIN_SHIFT;
static constexpr int SUB_SHIFT = 11;            // 2048-node accum subtile (24KB int LDS)
static constexpr int SUBSZ     = 1 << SUB_SHIFT;
static constexpr int NSUB      = BINSZ / SUBSZ; // 2
static constexpr int CAP       = 104;           // LDS bucket depth per super-bin (λ=84 +2.2σ)
static constexpr int BSTRIDE   = 105;           // padded bucket stride (840B, 16-bank spread)
static constexpr int CAPB      = 176;           // per-(bin,block) region capacity (λ=128 +4.2σ)
static constexpr int NBLKS     = 2048;          // scatter blocks
static constexpr int SSL       = 16;            // block-region slices per (bin,subtile)
static constexpr int BPS       = NBLKS / SSL;   // block-regions per slice (128)
static constexpr int MAXG      = 64;
static constexpr int SLOTS     = MAXG * 6;      // 384 stress accumulators
static constexpr int NWAVES    = TPB / 64;

static constexpr float VSCALE  = 4096.0f;       // virial fixed-point (2^12)
static constexpr float VINV    = 1.0f / 4096.0f;
static constexpr float FSCALE  = 1048576.0f;    // force tile fixed-point (2^20)
static constexpr float FINV    = 1.0f / 1048576.0f;
static constexpr float OSCALE  = 65536.0f;      // overflow fixed-point (2^16)
static constexpr float OINV    = 1.0f / 65536.0f;

// ------------------------------------------------ zero overflow array
__global__ __launch_bounds__(TPB) void zero_ovf_kernel(int4* __restrict__ p4, long n4) {
    long i = (long)blockIdx.x * TPB + threadIdx.x;
    const long gs = (long)gridDim.x * TPB;
    for (; i < n4; i += gs) p4[i] = make_int4(0, 0, 0, 0);
}

// --------------------- A: merged scatter + virial (staged, 2 groups/iter)
__device__ inline uint2 pack_rec(int node, float fx, float fy, float fz) {
    unsigned lid = (unsigned)node & (BINSZ - 1);    // 12-bit local id
    unsigned w0 = (unsigned)__half_as_ushort(__float2half(fx)) |
                  ((unsigned)__half_as_ushort(__float2half(fy)) << 16);
    unsigned w1 = (unsigned)__half_as_ushort(__float2half(fz)) | (lid << 16);
    return make_uint2(w0, w1);
}

__device__ inline void ovf_add(int* __restrict__ ovf, int node,
                               float fx, float fy, float fz) {
    atomicAdd(&ovf[3 * node + 0], __float2int_rn(fx * OSCALE));
    atomicAdd(&ovf[3 * node + 1], __float2int_rn(fy * OSCALE));
    atomicAdd(&ovf[3 * node + 2], __float2int_rn(fz * OSCALE));
}

__device__ inline void process_group(
    int k,
    const float4* __restrict__ rij4, const float4* __restrict__ fij4,
    const int4* __restrict__ i04, const int4* __restrict__ i14,
    const int* __restrict__ batch,
    uint2* __restrict__ buf, unsigned* __restrict__ cnt,
    int* __restrict__ s_acc, int* __restrict__ ovf) {
    int4 i0 = i04[k], i1 = i14[k];
    int s[4] = {i0.x, i0.y, i0.z, i0.w};
    int r[4] = {i1.x, i1.y, i1.z, i1.w};
    int gg[4];
#pragma unroll
    for (int e = 0; e < 4; ++e) gg[e] = batch[r[e]];

    float4 fa = fij4[3 * k], fb = fij4[3 * k + 1], fc = fij4[3 * k + 2];
    float4 ra = rij4[3 * k], rb = rij4[3 * k + 1], rc = rij4[3 * k + 2];
    float fx[4] = {fa.x, fa.w, fb.z, fc.y};
    float fy[4] = {fa.y, fb.x, fb.w, fc.z};
    float fz[4] = {fa.z, fb.y, fc.x, fc.w};
    float rx[4] = {ra.x, ra.w, rb.z, rc.y};
    float ry[4] = {ra.y, rb.x, rb.w, rc.z};
    float rz[4] = {ra.z, rb.y, rc.x, rc.w};

    // two-phase emit: pack all 8, issue all 8 LDS atomics, then stores
    int bb[8]; uint2 wv[8]; unsigned slot[8];
#pragma unroll
    for (int e = 0; e < 4; ++e) {
        bb[2 * e] = s[e] >> BIN_SHIFT;
        wv[2 * e] = pack_rec(s[e], fx[e], fy[e], fz[e]);
        bb[2 * e + 1] = r[e] >> BIN_SHIFT;
        wv[2 * e + 1] = pack_rec(r[e], -fx[e], -fy[e], -fz[e]);
    }
#pragma unroll
    for (int j = 0; j < 8; ++j)
        slot[j] = atomicAdd(&cnt[bb[j]], 1u);
#pragma unroll
    for (int j = 0; j < 8; ++j) {
        if (slot[j] < (unsigned)CAP) {
            buf[bb[j] * BSTRIDE + slot[j]] = wv[j];
        } else {
            int node = (bb[j] << BIN_SHIFT) | (int)(wv[j].y >> 16);
            float ox = __half2float(__ushort_as_half((unsigned short)(wv[j].x & 0xffffu)));
            float oy = __half2float(__ushort_as_half((unsigned short)(wv[j].x >> 16)));
            float oz = __half2float(__ushort_as_half((unsigned short)(wv[j].y & 0xffffu)));
            ovf_add(ovf, node, ox, oy, oz);
        }
    }
    // virial (int fixed-point LDS atomics)
#pragma unroll
    for (int e = 0; e < 4; ++e) {
        int* a = &s_acc[6 * gg[e]];
        atomicAdd(&a[0], __float2int_rn(rx[e] * fx[e] * VSCALE));
        atomicAdd(&a[1], __float2int_rn(ry[e] * fy[e] * VSCALE));
        atomicAdd(&a[2], __float2int_rn(rz[e] * fz[e] * VSCALE));
        atomicAdd(&a[3], __float2int_rn(rx[e] * fy[e] * VSCALE));
        atomicAdd(&a[4], __float2int_rn(ry[e] * fz[e] * VSCALE));
        atomicAdd(&a[5], __float2int_rn(rz[e] * fx[e] * VSCALE));
    }
}

__global__ __launch_bounds__(TPB) void scatter_kernel(
    const float* __restrict__ rij, const float* __restrict__ fij,
    const int* __restrict__ idx0, const int* __restrict__ idx1,
    const int* __restrict__ batch,
    uint2* __restrict__ rec, unsigned* __restrict__ cnt_out,
    int* __restrict__ ovf, float* __restrict__ apart,
    int E, int nbins) {
    extern __shared__ char smem[];
    uint2* buf = (uint2*)smem;                                   // nbins*BSTRIDE
    unsigned* cnt = (unsigned*)(buf + (size_t)nbins * BSTRIDE);  // nbins
    unsigned* loc = cnt + nbins;                                 // nbins
    int* s_acc = (int*)(loc + nbins);                            // SLOTS (int)

    for (int t = threadIdx.x; t < nbins; t += TPB) { cnt[t] = 0u; loc[t] = 0u; }
    for (int t = threadIdx.x; t < SLOTS; t += TPB) s_acc[t] = 0;
    __syncthreads();

    const int NG = E >> 2;
    const int GC = (NG + NBLKS - 1) / NBLKS;
    const int g0 = blockIdx.x * GC;
    int g1 = g0 + GC; if (g1 > NG) g1 = NG;
    const int span = g1 - g0;
    const int niter = span > 0 ? (span + 2 * TPB - 1) / (2 * TPB) : 0;

    const float4* fij4 = (const float4*)fij;
    const float4* rij4 = (const float4*)rij;
    const int4* i04 = (const int4*)idx0;
    const int4* i14 = (const int4*)idx1;

    const int wid = threadIdx.x >> 6, lane = threadIdx.x & 63;

    for (int it = 0; it < niter; ++it) {
        int kbase = g0 + it * 2 * TPB + threadIdx.x;
        if (kbase < g1)
            process_group(kbase, rij4, fij4, i04, i14, batch, buf, cnt, s_acc, ovf);
        if (kbase + TPB < g1)
            process_group(kbase + TPB, rij4, fij4, i04, i14, batch, buf, cnt, s_acc, ovf);
        __syncthreads();
        // flush: coalesced wave stores into this block's fixed per-bin region
        for (int b = wid; b < nbins; b += NWAVES) {
            unsigned c = cnt[b];
            unsigned m = c < (unsigned)CAP ? c : (unsigned)CAP;
            unsigned off0 = loc[b];
            for (unsigned base_l = 0; base_l < m; base_l += 64) {
                unsigned li = base_l + (unsigned)lane;
                if (li < m) {
                    unsigned sl_ = off0 + li;
                    uint2 w = buf[b * BSTRIDE + li];
                    if (sl_ < (unsigned)CAPB) {
                        rec[((size_t)b * NBLKS + blockIdx.x) * CAPB + sl_] = w;
                    } else {
                        int node = (b << BIN_SHIFT) | (int)(w.y >> 16);
                        float ox = __half2float(__ushort_as_half((unsigned short)(w.x & 0xffffu)));
                        float oy = __half2float(__ushort_as_half((unsigned short)(w.x >> 16)));
                        float oz = __half2float(__ushort_as_half((unsigned short)(w.y & 0xffffu)));
                        ovf_add(ovf, node, ox, oy, oz);
                    }
                }
            }
            if (lane == 0) {
                unsigned no = off0 + m;
                loc[b] = no < (unsigned)CAPB ? no : (unsigned)CAPB;
                cnt[b] = 0u;
            }
        }
        __syncthreads();
    }

    // scalar tail (E % 4): block 0, direct overflow path + virial
    if (blockIdx.x == 0) {
        for (int e = (NG << 2) + threadIdx.x; e < E; e += TPB) {
            float gx = fij[3 * e], gy = fij[3 * e + 1], gz = fij[3 * e + 2];
            int si = idx0[e], ri = idx1[e];
            ovf_add(ovf, si, gx, gy, gz);
            ovf_add(ovf, ri, -gx, -gy, -gz);
            float ex = rij[3 * e], ey = rij[3 * e + 1], ez = rij[3 * e + 2];
            int g = batch[ri];
            int* a = &s_acc[6 * g];
            atomicAdd(&a[0], __float2int_rn(ex * gx * VSCALE));
            atomicAdd(&a[1], __float2int_rn(ey * gy * VSCALE));
            atomicAdd(&a[2], __float2int_rn(ez * gz * VSCALE));
            atomicAdd(&a[3], __float2int_rn(ex * gy * VSCALE));
            atomicAdd(&a[4], __float2int_rn(ey * gz * VSCALE));
            atomicAdd(&a[5], __float2int_rn(ez * gx * VSCALE));
        }
    }

    __syncthreads();
    // per-(bin,block) record counts + virial partials
    for (int t = threadIdx.x; t < nbins; t += TPB)
        cnt_out[(size_t)t * NBLKS + blockIdx.x] = loc[t];
    for (int t = threadIdx.x; t < SLOTS; t += TPB)
        apart[(size_t)t * NBLKS + blockIdx.x] = (float)s_acc[t] * VINV;
}

// ------------------------------------------------------------- B: accumulate
__global__ __launch_bounds__(TPB) void bin_accum_kernel(
    const uint2* __restrict__ rec, const unsigned* __restrict__ cnt_out,
    float* __restrict__ bpart) {
    __shared__ int lf[SUBSZ * 3];                      // 24KB, fixed-point 2^20
    __shared__ unsigned scnt[BPS];
    const int sl = blockIdx.x % SSL;
    const int r2 = blockIdx.x / SSL;
    const int st = r2 & (NSUB - 1);
    const int bin = r2 >> 1;                           // NSUB == 2
    const int b0 = sl * BPS;

    int4* lf4 = (int4*)lf;
    for (int t = threadIdx.x; t < SUBSZ * 3 / 4; t += TPB)
        lf4[t] = make_int4(0, 0, 0, 0);
    for (int t = threadIdx.x; t < BPS; t += TPB)
        scnt[t] = cnt_out[(size_t)bin * NBLKS + b0 + t];
    __syncthreads();

    const int wid = threadIdx.x >> 6, lane = threadIdx.x & 63;

    // wave-per-region: 4 independent streams, full lane utilization
    for (int blk = wid; blk < BPS; blk += NWAVES) {
        unsigned c = scnt[blk];
        size_t base = ((size_t)bin * NBLKS + (b0 + blk)) * CAPB;
        for (unsigned r = (unsigned)lane; r < c; r += 64) {
            uint2 w = rec[base + r];
            unsigned lid = w.y >> 16;
            if ((int)(lid >> SUB_SHIFT) == st) {
                unsigned l2 = lid & (SUBSZ - 1);
                float fx = __half2float(__ushort_as_half((unsigned short)(w.x & 0xffffu)));
                float fy = __half2float(__ushort_as_half((unsigned short)(w.x >> 16)));
                float fz = __half2float(__ushort_as_half((unsigned short)(w.y & 0xffffu)));
                atomicAdd(&lf[l2 * 3 + 0], __float2int_rn(fx * FSCALE));
                atomicAdd(&lf[l2 * 3 + 1], __float2int_rn(fy * FSCALE));
                atomicAdd(&lf[l2 * 3 + 2], __float2int_rn(fz * FSCALE));
            }
        }
    }
    __syncthreads();
    float4* dst = (float4*)(bpart + (size_t)blockIdx.x * (SUBSZ * 3));
    for (int t = threadIdx.x; t < SUBSZ * 3 / 4; t += TPB) {
        int4 v = lf4[t];
        dst[t] = make_float4((float)v.x * FINV, (float)v.y * FINV,
                             (float)v.z * FINV, (float)v.w * FINV);
    }
}

// ------------------------------------------------------------- C: force out
__global__ __launch_bounds__(TPB) void force_kernel(
    const float* __restrict__ bpart, const int* __restrict__ ovf,
    const float* __restrict__ pos_grad,
    float* __restrict__ force, long n3) {
    long j = (long)blockIdx.x * TPB + threadIdx.x;
    const long gs = (long)gridDim.x * TPB;
    for (; j < n3; j += gs) {
        unsigned i = (unsigned)(j / 3);
        unsigned c = (unsigned)(j - 3L * i);
        unsigned bin = i >> BIN_SHIFT;
        unsigned st = (i >> SUB_SHIFT) & (NSUB - 1);
        unsigned l2 = i & (SUBSZ - 1);
        float acc = -pos_grad[j] + (float)ovf[j] * OINV;
        size_t tb = ((size_t)(bin * NSUB + st) * SSL) * (SUBSZ * 3) + l2 * 3 + c;
#pragma unroll
        for (int sl = 0; sl < SSL; ++sl)
            acc += bpart[tb + (size_t)sl * (SUBSZ * 3)];
        force[j] = acc;
    }
}

// ------------------------------------------------------------- R: stress out
__global__ __launch_bounds__(TPB) void stress_kernel(
    const float* __restrict__ apart,
    const float* __restrict__ cell_grad, const float* __restrict__ les_cell,
    const float* __restrict__ vol, float* __restrict__ stress, int slots) {
    int t = blockIdx.x;
    if (t >= slots) return;
    __shared__ float red[TPB];
    float s = 0.f;
    const float* row = apart + (size_t)t * NBLKS;
    for (int j = threadIdx.x; j < NBLKS; j += TPB) s += row[j];
    red[threadIdx.x] = s;
    __syncthreads();
    for (int w = TPB / 2; w > 0; w >>= 1) {
        if (threadIdx.x < w) red[threadIdx.x] += red[threadIdx.x + w];
        __syncthreads();
    }
    if (threadIdx.x == 0) {
        int g = t / 6, c = t - 6 * g;
        const int va[6] = {0, 1, 2, 0, 1, 0};
        const int vb[6] = {0, 1, 2, 1, 2, 2};
        int a = va[c], bb = vb[c];
        const float* L = les_cell + 9 * g;
        const float* Gm = cell_grad + 9 * g;
        float lr = L[a] * Gm[bb] + L[3 + a] * Gm[3 + bb] + L[6 + a] * Gm[6 + bb];
        stress[t] = (-red[0] - lr) / vol[g];
    }
}

// ---------------------------------------------------- fallback (round-1 path)
__global__ void init_force_kernel(const float4* __restrict__ pg4,
                                  float4* __restrict__ f4, int n4,
                                  const float* __restrict__ pg,
                                  float* __restrict__ f, int n) {
    int i = blockIdx.x * blockDim.x + threadIdx.x;
    int s = gridDim.x * blockDim.x;
    for (int k = i; k < n4; k += s) {
        float4 v = pg4[k];
        f4[k] = make_float4(-v.x, -v.y, -v.z, -v.w);
    }
    for (int k = n4 * 4 + i; k < n; k += s) f[k] = -pg[k];
}

__global__ __launch_bounds__(256) void edge_dev_kernel(
    const float* __restrict__ rij, const float* __restrict__ fij,
    const int* __restrict__ idx0, const int* __restrict__ idx1,
    const int* __restrict__ batch,
    float* __restrict__ force, float* __restrict__ partials, int E) {
    __shared__ float s_acc[SLOTS];
    for (int t = threadIdx.x; t < SLOTS; t += blockDim.x) s_acc[t] = 0.0f;
    __syncthreads();
    const int stride = gridDim.x * blockDim.x;
    const int tid0 = blockIdx.x * blockDim.x + threadIdx.x;
    for (int e = tid0; e < E; e += stride) {
        float ex = rij[3 * e], ey = rij[3 * e + 1], ez = rij[3 * e + 2];
        float gx = fij[3 * e], gy = fij[3 * e + 1], gz = fij[3 * e + 2];
        int si = idx0[e], ri = idx1[e];
        atomicAdd(&force[3 * si + 0], gx);
        atomicAdd(&force[3 * si + 1], gy);
        atomicAdd(&force[3 * si + 2], gz);
        atomicAdd(&force[3 * ri + 0], -gx);
        atomicAdd(&force[3 * ri + 1], -gy);
        atomicAdd(&force[3 * ri + 2], -gz);
        int g = batch[ri];
        float* a = &s_acc[6 * g];
        atomicAdd(&a[0], ex * gx);
        atomicAdd(&a[1], ey * gy);
        atomicAdd(&a[2], ez * gz);
        atomicAdd(&a[3], ex * gy);
        atomicAdd(&a[4], ey * gz);
        atomicAdd(&a[5], ez * gx);
    }
    __syncthreads();
    for (int t = threadIdx.x; t < SLOTS; t += blockDim.x)
        partials[(size_t)blockIdx.x * SLOTS + t] = s_acc[t];
}

__global__ void reduce_finalize_kernel(const float* __restrict__ partials, int nblocks,
                                       const float* __restrict__ cell_grad,
                                       const float* __restrict__ les_cell,
                                       const float* __restrict__ vol,
                                       float* __restrict__ stress_out, int slots) {
    int t = blockIdx.x * blockDim.x + threadIdx.x;
    if (t >= slots) return;
    float s = 0.0f;
    for (int b = 0; b < nblocks; ++b) s += partials[(size_t)b * SLOTS + t];
    int g = t / 6, c = t - 6 * g;
    const int va[6] = {0, 1, 2, 0, 1, 0};
    const int vb[6] = {0, 1, 2, 1, 2, 2};
    int a = va[c], bb = vb[c];
    const float* L = les_cell + 9 * g;
    const float* G = cell_grad + 9 * g;
    float lr = L[a] * G[bb] + L[3 + a] * G[3 + bb] + L[6 + a] * G[6 + bb];
    stress_out[t] = (-s - lr) / vol[g];
}

// ------------------------------------------------------------------ launcher
static inline size_t alignup(size_t x) { return (x + 255) & ~(size_t)255; }

extern "C" void kernel_launch(void* const* d_in, const int* in_sizes, int n_in,
                              void* d_out, int out_size, void* d_ws, size_t ws_size,
                              hipStream_t stream) {
    const float* rij = (const float*)d_in[0];
    const float* fij = (const float*)d_in[1];
    const float* pos_grad = (const float*)d_in[2];
    const float* cell_grad = (const float*)d_in[3];
    const float* les_cell = (const float*)d_in[4];
    const float* vol = (const float*)d_in[5];
    const int* edge_idx = (const int*)d_in[6];
    const int* batch = (const int*)d_in[7];

    const int E = in_sizes[0] / 3;
    const int N = in_sizes[2] / 3;
    const int ngr = in_sizes[5];
    const int slots = 6 * ngr;

    float* force = (float*)d_out;
    float* stress = (float*)d_out + (size_t)N * 3;

    const int nbins = (N + BINSZ - 1) >> BIN_SHIFT;
    const long N3 = (long)N * 3;

    const size_t rec_elems = (size_t)nbins * NBLKS * CAPB;

    // workspace layout
    size_t off = 0;
    const size_t o_rec = off;    off += alignup(rec_elems * 8);
    const size_t o_cnt = off;    off += alignup((size_t)nbins * NBLKS * 4);
    const size_t o_ovf = off;    off += alignup(((size_t)N3 + 4) * 4);
    const size_t o_apart = off;  off += alignup((size_t)SLOTS * NBLKS * 4);
    const size_t o_bpart = off;  off += alignup((size_t)nbins * NSUB * SSL * (SUBSZ * 3) * 4);
    const bool fit = (off <= ws_size) && (nbins <= MAXB) && (ngr <= MAXG) && (E >= 4);

    if (fit) {
        char* ws = (char*)d_ws;
        uint2* rec = (uint2*)(ws + o_rec);
        unsigned* cnt_out = (unsigned*)(ws + o_cnt);
        int* ovf = (int*)(ws + o_ovf);
        float* apart = (float*)(ws + o_apart);
        float* bpart = (float*)(ws + o_bpart);

        long n4 = (N3 + 3) / 4;
        int zb = (int)((n4 + TPB - 1) / TPB); if (zb > 2048) zb = 2048; if (zb < 1) zb = 1;
        zero_ovf_kernel<<<zb, TPB, 0, stream>>>((int4*)ovf, n4);

        const size_t smem = (size_t)nbins * BSTRIDE * 8 + (size_t)nbins * 8 + SLOTS * 4;
        scatter_kernel<<<NBLKS, TPB, smem, stream>>>(
            rij, fij, edge_idx, edge_idx + E, batch, rec, cnt_out, ovf, apart,
            E, nbins);

        bin_accum_kernel<<<nbins * NSUB * SSL, TPB, 0, stream>>>(rec, cnt_out, bpart);

        int fblocks = (int)((N3 + TPB - 1) / TPB);
        if (fblocks > 4096) fblocks = 4096;
        force_kernel<<<fblocks, TPB, 0, stream>>>(bpart, ovf, pos_grad, force, N3);

        stress_kernel<<<slots, TPB, 0, stream>>>(apart, cell_grad, les_cell, vol,
                                                 stress, slots);
    } else {
        // device-atomic fallback (proven correct, slow)
        float* partials = (float*)d_ws;
        int eblocks = 512;
        size_t need = (size_t)eblocks * SLOTS * sizeof(float);
        if (need > ws_size) {
            int fit2 = (int)(ws_size / (SLOTS * sizeof(float)));
            eblocks = fit2 > 0 ? fit2 : 1;
        }
        int n = (int)N3, n4 = n / 4;
        int blocks = (n4 + 255) / 256;
        if (blocks > 1024) blocks = 1024;
        if (blocks < 1) blocks = 1;
        init_force_kernel<<<blocks, 256, 0, stream>>>(
            (const float4*)pos_grad, (float4*)force, n4, pos_grad, force, n);
        edge_dev_kernel<<<eblocks, 256, 0, stream>>>(rij, fij, edge_idx, edge_idx + E,
                                                     batch, force, partials, E);
        reduce_finalize_kernel<<<6, 64, 0, stream>>>(partials, eblocks, cell_grad,
                                                     les_cell, vol, stress, slots);
    }
}